// Round 1
// baseline (15720.874 us; speedup 1.0000x reference)
//
#include <hip/hip_runtime.h>
#include <hip/hip_bf16.h>
#include <math.h>

#define VDIM 128
#define HDIM 512
#define BATCH 512
#define RPB 4                 // batch rows per block
#define NBLK (BATCH / RPB)    // 128 blocks
#define NT 512                // threads per block (8 waves)
#define NWAVE (NT / 64)
#define LN_EPS 1e-5f

struct Params {
    const float *u;
    const float *q_w1, *q_b1, *q_g1, *q_be1;
    const float *q_w2, *q_b2, *q_g2, *q_be2;
    const float *q_w3, *q_b3, *q_g3, *q_be3;
    const float *q_W, *q_bias, *q_marg;
    const float *f_w1, *f_b1, *f_g1, *f_be1;
    const float *f_w2, *f_b2, *f_g2, *f_be2;
    const float *f_w3, *f_b3, *f_g3, *f_be3;
    const float *f_w4, *f_b4, *J;
    const int *top_order, *pa_mask;
    float *V_out, *lp, *lf, *score, *loss;
};

// Deterministic block-wide sum of 4 independent values (one per row).
__device__ __forceinline__ float4 block_reduce4(float4 v, float4 *red, int tid) {
#pragma unroll
    for (int off = 1; off < 64; off <<= 1) {
        v.x += __shfl_xor(v.x, off, 64);
        v.y += __shfl_xor(v.y, off, 64);
        v.z += __shfl_xor(v.z, off, 64);
        v.w += __shfl_xor(v.w, off, 64);
    }
    if ((tid & 63) == 0) red[tid >> 6] = v;
    __syncthreads();
    float4 s = red[0];
#pragma unroll
    for (int w = 1; w < NWAVE; ++w) {
        float4 t = red[w];
        s.x += t.x; s.y += t.y; s.z += t.z; s.w += t.w;
    }
    __syncthreads();
    return s;
}

__device__ __forceinline__ float block_reduce1(float v, float *red, int tid) {
#pragma unroll
    for (int off = 1; off < 64; off <<= 1) v += __shfl_xor(v, off, 64);
    if ((tid & 63) == 0) red[tid >> 6] = v;
    __syncthreads();
    float s = 0.f;
#pragma unroll
    for (int w = 0; w < NWAVE; ++w) s += red[w];
    __syncthreads();
    return s;
}

// OT[c] = relu(LN(AT^T @ W + b) * g + be) for 4 rows at once.
// AT: LDS [K] float4 (input activations, transposed: AT[k] = 4 rows' value at k)
// W : global [K][HDIM] row-major.  thread tid owns column c = tid.
template <int K>
__device__ __forceinline__ void gemv_ln(const float4 *__restrict__ AT,
                                        const float *__restrict__ W,
                                        const float *__restrict__ bias,
                                        const float *__restrict__ gam,
                                        const float *__restrict__ bet,
                                        float4 *__restrict__ OT,
                                        float4 *red, int tid) {
    const float *Wc = W + tid;
    float4 acc = make_float4(0.f, 0.f, 0.f, 0.f);
#pragma unroll 8
    for (int k = 0; k < K; ++k) {
        float4 a = AT[k];                 // LDS broadcast
        float w = Wc[k * HDIM];           // coalesced across threads
        acc.x = fmaf(a.x, w, acc.x);
        acc.y = fmaf(a.y, w, acc.y);
        acc.z = fmaf(a.z, w, acc.z);
        acc.w = fmaf(a.w, w, acc.w);
    }
    float bc = bias[tid];
    acc.x += bc; acc.y += bc; acc.z += bc; acc.w += bc;

    // two-pass LN over the 512 columns (matches reference: mean, then ((x-m)^2).mean)
    const float inv = 1.f / (float)HDIM;
    float4 s1 = block_reduce4(acc, red, tid);
    float4 d;
    d.x = acc.x - s1.x * inv;
    d.y = acc.y - s1.y * inv;
    d.z = acc.z - s1.z * inv;
    d.w = acc.w - s1.w * inv;
    float4 sq = make_float4(d.x * d.x, d.y * d.y, d.z * d.z, d.w * d.w);
    float4 s2 = block_reduce4(sq, red, tid);
    float4 rs;
    rs.x = 1.f / sqrtf(s2.x * inv + LN_EPS);
    rs.y = 1.f / sqrtf(s2.y * inv + LN_EPS);
    rs.z = 1.f / sqrtf(s2.z * inv + LN_EPS);
    rs.w = 1.f / sqrtf(s2.w * inv + LN_EPS);
    float gc = gam[tid], ec = bet[tid];
    float4 h;
    h.x = fmaxf(fmaf(d.x * rs.x, gc, ec), 0.f);
    h.y = fmaxf(fmaf(d.y * rs.y, gc, ec), 0.f);
    h.z = fmaxf(fmaf(d.z * rs.z, gc, ec), 0.f);
    h.w = fmaxf(fmaf(d.w * rs.w, gc, ec), 0.f);
    OT[tid] = h;
    __syncthreads();
}

__global__ __launch_bounds__(NT) void gfn_scan(Params P) {
    __shared__ float4 VT[VDIM];    // V^T   [k][4 rows]
    __shared__ float4 VPT[VDIM];   // V_pa^T
    __shared__ float4 HA[HDIM];
    __shared__ float4 HB[HDIM];
    __shared__ float4 red[NWAVE];

    const int tid = threadIdx.x;
    const int row0 = blockIdx.x * RPB;

    if (tid < VDIM) VT[tid] = make_float4(0.f, 0.f, 0.f, 0.f);
    __syncthreads();

    for (int i = 0; i < VDIM; ++i) {
        const int node = P.top_order[i];

        // V_pa = V * mask_row(node); empty-check partials
        float4 ap = make_float4(0.f, 0.f, 0.f, 0.f);
        if (tid < VDIM) {
            float mk = (float)P.pa_mask[node * VDIM + tid];
            float4 v = VT[tid];
            float4 vp = make_float4(v.x * mk, v.y * mk, v.z * mk, v.w * mk);
            VPT[tid] = vp;
            ap = make_float4(fabsf(vp.x), fabsf(vp.y), fabsf(vp.z), fabsf(vp.w));
        }
        float4 asum = block_reduce4(ap, red, tid);  // also makes VPT visible

        // qtrunk
        gemv_ln<VDIM>(VPT, P.q_w1, P.q_b1, P.q_g1, P.q_be1, HA, red, tid);
        gemv_ln<HDIM>(HA, P.q_w2, P.q_b2, P.q_g2, P.q_be2, HB, red, tid);
        gemv_ln<HDIM>(HB, P.q_w3, P.q_b3, P.q_g3, P.q_be3, HA, red, tid);

        // head: x = h3 @ q_W[node] + q_bias[node]
        float4 h3 = HA[tid];
        float wq = P.q_W[node * HDIM + tid];
        float4 xp = make_float4(h3.x * wq, h3.y * wq, h3.z * wq, h3.w * wq);
        float4 x4 = block_reduce4(xp, red, tid);

        if (tid < RPB) {
            const int r = tid;
            float asr = (r == 0) ? asum.x : (r == 1) ? asum.y : (r == 2) ? asum.z : asum.w;
            float xr  = (r == 0) ? x4.x  : (r == 1) ? x4.y  : (r == 2) ? x4.z  : x4.w;
            xr += P.q_bias[node];
            float arg = (asr == 0.f) ? P.q_marg[node] : xr;   // empty -> marginal
            float p = 1.f / (1.f + expf(-arg));
            float uv = P.u[i * BATCH + row0 + r];             // u NOT permuted by top_order
            bool samp = uv < p;
            ((float *)&VT[node])[r] = samp ? 1.f : -1.f;      // scatter into column `node`
            P.lp[i * BATCH + row0 + r] = samp ? logf(p) : log1pf(-p);
        }
        __syncthreads();

        // fnet(V_new)
        gemv_ln<VDIM>(VT, P.f_w1, P.f_b1, P.f_g1, P.f_be1, HB, red, tid);
        gemv_ln<HDIM>(HB, P.f_w2, P.f_b2, P.f_g2, P.f_be2, HA, red, tid);
        gemv_ln<HDIM>(HA, P.f_w3, P.f_b3, P.f_g3, P.f_be3, HB, red, tid);

        float4 hf = HB[tid];
        float wf = P.f_w4[tid];
        float4 fp = make_float4(hf.x * wf, hf.y * wf, hf.z * wf, hf.w * wf);
        float4 lf4 = block_reduce4(fp, red, tid);
        if (tid < RPB) {
            float lfv = ((tid == 0) ? lf4.x : (tid == 1) ? lf4.y : (tid == 2) ? lf4.z : lf4.w)
                        + P.f_b4[0];
            P.lf[i * BATCH + row0 + tid] = lfv;
        }
        // reduce already ended with __syncthreads(); VT stable for next iter
    }

    // terminal score: V J V^T per row
    float4 sc = make_float4(0.f, 0.f, 0.f, 0.f);
    for (int idx = tid; idx < VDIM * VDIM; idx += NT) {
        int ii = idx >> 7, jj = idx & (VDIM - 1);
        float jv = P.J[idx];
        float4 vi = VT[ii], vj = VT[jj];
        sc.x = fmaf(vi.x * jv, vj.x, sc.x);
        sc.y = fmaf(vi.y * jv, vj.y, sc.y);
        sc.z = fmaf(vi.z * jv, vj.z, sc.z);
        sc.w = fmaf(vi.w * jv, vj.w, sc.w);
    }
    float4 sc4 = block_reduce4(sc, red, tid);
    if (tid < RPB) {
        float s = (tid == 0) ? sc4.x : (tid == 1) ? sc4.y : (tid == 2) ? sc4.z : sc4.w;
        P.score[row0 + tid] = s;
    }
    if (tid < VDIM) {
        float4 v = VT[tid];
        P.V_out[(row0 + 0) * VDIM + tid] = v.x;
        P.V_out[(row0 + 1) * VDIM + tid] = v.y;
        P.V_out[(row0 + 2) * VDIM + tid] = v.z;
        P.V_out[(row0 + 3) * VDIM + tid] = v.w;
    }
}

// One block: F0 = fnet(0), then assemble log_flow and reduce the loss.
__global__ __launch_bounds__(NT) void gfn_loss(Params P) {
    __shared__ float H1[HDIM], H2[HDIM];
    __shared__ float red1[NWAVE];
    const int tid = threadIdx.x;
    const float inv = 1.f / (float)HDIM;

    // F0 = fnet(zeros): layer1 input is 0 -> z = b1
    float z = P.f_b1[tid];
    float m = block_reduce1(z, red1, tid) * inv;
    float d = z - m;
    float var = block_reduce1(d * d, red1, tid) * inv;
    float h = fmaxf(fmaf(d * (1.f / sqrtf(var + LN_EPS)), P.f_g1[tid], P.f_be1[tid]), 0.f);
    H1[tid] = h;
    __syncthreads();

    float acc = 0.f;
    for (int k = 0; k < HDIM; ++k) acc = fmaf(H1[k], P.f_w2[k * HDIM + tid], acc);
    z = acc + P.f_b2[tid];
    m = block_reduce1(z, red1, tid) * inv;
    d = z - m;
    var = block_reduce1(d * d, red1, tid) * inv;
    h = fmaxf(fmaf(d * (1.f / sqrtf(var + LN_EPS)), P.f_g2[tid], P.f_be2[tid]), 0.f);
    H2[tid] = h;
    __syncthreads();

    acc = 0.f;
    for (int k = 0; k < HDIM; ++k) acc = fmaf(H2[k], P.f_w3[k * HDIM + tid], acc);
    z = acc + P.f_b3[tid];
    m = block_reduce1(z, red1, tid) * inv;
    d = z - m;
    var = block_reduce1(d * d, red1, tid) * inv;
    h = fmaxf(fmaf(d * (1.f / sqrtf(var + LN_EPS)), P.f_g3[tid], P.f_be3[tid]), 0.f);
    float F0 = block_reduce1(h * P.f_w4[tid], red1, tid) + P.f_b4[0];

    // loss: thread tid owns batch element b = tid
    const int b = tid;
    float lfp = F0;
    float s = 0.f;
    for (int t = 0; t < VDIM; ++t) {
        float lp = P.lp[t * BATCH + b];
        float lfn = (t == VDIM - 1) ? P.score[b] : P.lf[t * BATCH + b];
        float dd = lfp + lp - lfn;
        s = fmaf(dd, dd, s);
        lfp = lfn;
    }
    s *= (1.f / (float)VDIM);
    float total = block_reduce1(s, red1, tid) * (1.f / (float)BATCH);
    if (tid == 0) P.loss[0] = total;
}

extern "C" void kernel_launch(void *const *d_in, const int *in_sizes, int n_in,
                              void *d_out, int out_size, void *d_ws, size_t ws_size,
                              hipStream_t stream) {
    Params P;
    P.u     = (const float *)d_in[0];
    P.q_w1  = (const float *)d_in[1];
    P.q_b1  = (const float *)d_in[2];
    P.q_g1  = (const float *)d_in[3];
    P.q_be1 = (const float *)d_in[4];
    P.q_w2  = (const float *)d_in[5];
    P.q_b2  = (const float *)d_in[6];
    P.q_g2  = (const float *)d_in[7];
    P.q_be2 = (const float *)d_in[8];
    P.q_w3  = (const float *)d_in[9];
    P.q_b3  = (const float *)d_in[10];
    P.q_g3  = (const float *)d_in[11];
    P.q_be3 = (const float *)d_in[12];
    P.q_W   = (const float *)d_in[13];
    P.q_bias= (const float *)d_in[14];
    P.q_marg= (const float *)d_in[15];
    P.f_w1  = (const float *)d_in[16];
    P.f_b1  = (const float *)d_in[17];
    P.f_g1  = (const float *)d_in[18];
    P.f_be1 = (const float *)d_in[19];
    P.f_w2  = (const float *)d_in[20];
    P.f_b2  = (const float *)d_in[21];
    P.f_g2  = (const float *)d_in[22];
    P.f_be2 = (const float *)d_in[23];
    P.f_w3  = (const float *)d_in[24];
    P.f_b3  = (const float *)d_in[25];
    P.f_g3  = (const float *)d_in[26];
    P.f_be3 = (const float *)d_in[27];
    P.f_w4  = (const float *)d_in[28];
    P.f_b4  = (const float *)d_in[29];
    P.J     = (const float *)d_in[30];
    P.top_order = (const int *)d_in[31];
    P.pa_mask   = (const int *)d_in[32];

    float *ws = (float *)d_ws;
    P.V_out = (float *)d_out;
    P.loss  = (float *)d_out + (size_t)BATCH * VDIM;   // d_out[65536]
    P.lp    = ws;                                      // [VDIM][BATCH]
    P.lf    = ws + (size_t)VDIM * BATCH;               // [VDIM][BATCH]
    P.score = ws + 2 * (size_t)VDIM * BATCH;           // [BATCH]

    gfn_scan<<<dim3(NBLK), dim3(NT), 0, stream>>>(P);
    gfn_loss<<<dim3(1), dim3(NT), 0, stream>>>(P);
}